// Round 19
// baseline (157.858 us; speedup 1.0000x reference)
//
#include <hip/hip_runtime.h>

// Encoder block: x:(4,1024,1024) f32. Fused-QKV proj -> MHA(16 heads) -> Wo -> +res -> norm
// (ddof=1) -> FF(relu) -> +res -> norm. bf16 MFMA GEMMs, fp32 norms.
// R19: QKV GEMM -> BM=128/BN=64 (16 MFMA/barrier, 2x amortization; grid 1536, XCD remap
// with 1MB A-slice). Small GEMMs stay BM=64 (R18). Attn/norms/cvt unchanged.

typedef __bf16 bf16x8 __attribute__((ext_vector_type(8)));
typedef float f32x4 __attribute__((ext_vector_type(4)));
typedef unsigned short ushort4v __attribute__((ext_vector_type(4)));
typedef unsigned short ushort8v __attribute__((ext_vector_type(8)));

static __device__ __forceinline__ unsigned short f2bf(float f) {
  return __builtin_bit_cast(unsigned short, (__bf16)f);  // HW RNE cvt
}
static __device__ __forceinline__ float bf2f(unsigned short u) {
  return __builtin_bit_cast(float, (unsigned int)u << 16);
}

static __device__ __forceinline__ void gload_lds16(const void* g, void* l) {
  __builtin_amdgcn_global_load_lds(
      (const __attribute__((address_space(1))) unsigned int*)g,
      (__attribute__((address_space(3))) unsigned int*)l, 16, 0, 0);
}

// One launch: y=0..3 -> x quarters; y=4..6 -> Wq/Wk/Wv into concat; y=7..9 -> Wo/W1/W2.
__global__ __launch_bounds__(256)
void cvt_all(const float* __restrict__ x, const float* __restrict__ wq,
             const float* __restrict__ wk, const float* __restrict__ wv,
             const float* __restrict__ wo, const float* __restrict__ w1,
             const float* __restrict__ w2,
             unsigned short* __restrict__ x_bf, unsigned short* __restrict__ wqkv_bf,
             unsigned short* __restrict__ wo_bf, unsigned short* __restrict__ w1_bf,
             unsigned short* __restrict__ w2_bf) {
  const int y = blockIdx.y;
  const size_t MEL = 1u << 20;
  const float* src;
  unsigned short* dst;
  switch (y) {
    case 0: case 1: case 2: case 3: src = x + y * MEL; dst = x_bf + y * MEL; break;
    case 4: src = wq; dst = wqkv_bf; break;
    case 5: src = wk; dst = wqkv_bf + MEL; break;
    case 6: src = wv; dst = wqkv_bf + 2 * MEL; break;
    case 7: src = wo; dst = wo_bf; break;
    case 8: src = w1; dst = w1_bf; break;
    default: src = w2; dst = w2_bf; break;
  }
  const int i = blockIdx.x * 256 + threadIdx.x;
  const float4 v = reinterpret_cast<const float4*>(src)[i];
  ushort4v o;
  o[0] = f2bf(v.x); o[1] = f2bf(v.y); o[2] = f2bf(v.z); o[3] = f2bf(v.w);
  reinterpret_cast<ushort4v*>(dst)[i] = o;
}

// C[M,N] = A[M,K] @ W[N,K]^T + bias. BM=BMT, BN=64, BK=64, 4 waves (2x2),
// wave tile (BMT/2) x 32. 2-phase dbuf LDS, one barrier per K-step, prefetch under MFMAs,
// XOR-swizzled LDS (16B chunk c of row r holds k-chunk c^(r&7)).
// 1D grid, XCD-partitioned remap (M==4096): XCD owns a contiguous row-panel slice
// (1MB of A, L2-resident) and sweeps columns.
// BMT=64: OUT_MODE 1 (bf16 rm scalar stores, opt RELU); 32KB LDS, 4 blocks/CU.
// BMT=128: OUT_MODE 2 (fused QKV split, LDS-coalesced epilogue; seg=bCol>>10:
//   0 Q rm prescaled by 0.125*log2e, 1 K rm, 2 V^T [(b*16+h)][d][s]); 48KB LDS.
template<int BMT, bool RELU, int OUT_MODE>
__global__ __launch_bounds__(256, (BMT == 64 ? 4 : 2))
void gemm_bt(const unsigned short* __restrict__ A,
             const unsigned short* __restrict__ W,
             const float* __restrict__ bias0, const float* __restrict__ bias1,
             const float* __restrict__ bias2,
             void* __restrict__ out0, unsigned short* __restrict__ outK,
             unsigned short* __restrict__ outVt, int M, int N, int K) {
  constexpr int MFR = BMT / 32;                 // M-frags per wave
  __shared__ __align__(16) unsigned short Al[2][BMT][64];
  __shared__ __align__(16) unsigned short Bl[2][64][64];
  const int tid = threadIdx.x;
  const int lane = tid & 63;
  const int w = tid >> 6;
  const int wr = w >> 1, wc = w & 1;
  const int grp = lane >> 4, l15 = lane & 15;
  // XCD-partitioned decomposition of the 1D block id
  const int bid = blockIdx.x;
  const int xcd = bid & 7;
  const int li = bid >> 3;
  long bRow, bCol;
  if constexpr (BMT == 64) {        // 64 row-panels: XCD owns 8
    bRow = (long)(xcd * 8 + (li & 7)) * 64;
    bCol = (long)(li >> 3) * 64;
  } else {                          // 32 row-panels: XCD owns 4
    bRow = (long)(xcd * 4 + (li & 3)) * 128;
    bCol = (long)(li >> 2) * 64;
  }

  f32x4 acc[MFR][2];
#pragma unroll
  for (int m = 0; m < MFR; m++)
#pragma unroll
    for (int n = 0; n < 2; n++) { f32x4 z = {0.f,0.f,0.f,0.f}; acc[m][n] = z; }

  const int srow = tid >> 3;                    // 0..31 (32 rows per gload round)
  const int xc = (((tid & 7) ^ (srow & 7)) << 3);
  const unsigned short* Ag = A + (bRow + srow) * (long)K + xc;
  const unsigned short* Wg = W + (bCol + srow) * (long)K + xc;

  auto stage = [&](int k0, int buf) {
    unsigned short* ldsA = &Al[buf][0][0] + w * 512;   // wave-uniform base
    unsigned short* ldsB = &Bl[buf][0][0] + w * 512;
#pragma unroll
    for (int r = 0; r < BMT / 32; r++)
      gload_lds16(Ag + r * 32L * K + k0, ldsA + r * 2048);
#pragma unroll
    for (int r = 0; r < 2; r++)
      gload_lds16(Wg + r * 32L * K + k0, ldsB + r * 2048);
  };

  const int NT = K >> 6;
  stage(0, 0);
  for (int t = 0; t < NT; ++t) {
    const int cur = t & 1;
    __syncthreads();  // drains vmcnt: buf[cur] resident; buf[cur^1] readers (t-1) done
    if (t + 1 < NT) stage((t + 1) << 6, cur ^ 1);  // in flight under MFMAs
#pragma unroll
    for (int kk = 0; kk < 2; kk++) {
      bf16x8 af[MFR], bfr[2];
#pragma unroll
      for (int m = 0; m < MFR; m++) {
        const int R = wr * (BMT / 2) + m * 16 + l15;
        const int pos = (kk * 4 + grp) ^ (R & 7);
        af[m] = *(const bf16x8*)&Al[cur][R][pos << 3];
      }
#pragma unroll
      for (int n = 0; n < 2; n++) {
        const int R = wc * 32 + n * 16 + l15;
        const int pos = (kk * 4 + grp) ^ (R & 7);
        bfr[n] = *(const bf16x8*)&Bl[cur][R][pos << 3];
      }
#pragma unroll
      for (int m = 0; m < MFR; m++)
#pragma unroll
        for (int n = 0; n < 2; n++)
          acc[m][n] = __builtin_amdgcn_mfma_f32_16x16x32_bf16(af[m], bfr[n], acc[m][n], 0, 0, 0);
    }
  }

  const float QSCL = 0.125f * 1.44269504088896340736f;  // folded softmax scale (seg 0)

  if (OUT_MODE == 1) {
    // direct scalar stores (small GEMMs, BMT=64)
#pragma unroll
    for (int n = 0; n < 2; n++) {
      const long col = bCol + wc * 32 + n * 16 + l15;
      const float bv = bias0[col];
#pragma unroll
      for (int m = 0; m < MFR; m++) {
        const long row0 = bRow + wr * (BMT / 2) + m * 16 + grp * 4;
#pragma unroll
        for (int r = 0; r < 4; r++) {
          float v = acc[m][n][r] + bv;
          if (RELU) v = fmaxf(v, 0.f);
          ((unsigned short*)out0)[(row0 + r) * (long)N + col] = f2bf(v);
        }
      }
    }
  } else {
    // QKV (BMT=128): epilogue through LDS (Al reused; 16KB C-tile) -> coalesced stores
    const int seg = (int)(bCol >> 10);
    const float* bp = (seg == 0 ? bias0 : seg == 1 ? bias1 : bias2);
    unsigned short* Cl = &Al[0][0][0];
    __syncthreads();  // all frag reads done; Al reusable
#pragma unroll
    for (int n = 0; n < 2; n++) {
      const int cc = wc * 32 + n * 16 + l15;            // 0..63 block-col
      const long col = bCol + cc;
      const float bv = bp[col & 1023];
#pragma unroll
      for (int m = 0; m < MFR; m++) {
        const int row0 = wr * (BMT / 2) + m * 16 + grp * 4;   // block-row 0..127
#pragma unroll
        for (int r = 0; r < 4; r++) {
          const int rl = row0 + r;
          float v = acc[m][n][r] + bv;
          if (seg == 0) v *= QSCL;
          if (seg == 2) Cl[cc * BMT + (rl ^ ((cc & 7) << 3))] = f2bf(v);  // swz [64][128]
          else          Cl[rl * 64 + cc] = f2bf(v);                       // [128][64]
        }
      }
    }
    __syncthreads();
    if (seg == 2) {
      // V^T out: [(b*16+h)][d=cc][s]; block spans one head slab; 128 s per cc
      const int cc = tid >> 2;              // 0..63
      const int part = tid & 3;             // 32 s-values each
      const long bidx = (bRow >> 10) * 16 + (((long)(bCol & 1023)) >> 6);
      unsigned short* dst = outVt + (bidx << 16) + ((long)cc << 10) +
                            (bRow & 1023) + part * 32;
#pragma unroll
      for (int k = 0; k < 4; k++) {
        const int g = part * 4 + k;         // s-group: rows g*8..g*8+7
        *(ushort8v*)(dst + k * 8) =
            *(const ushort8v*)(Cl + cc * BMT + ((g ^ (cc & 7)) << 3));
      }
    } else {
      const int rl = tid >> 1;              // 0..127
      const int half = tid & 1;             // 32-col half
      const unsigned short* srcp = Cl + rl * 64 + half * 32;
      unsigned short* dst;
      if (seg == 0) dst = (unsigned short*)out0 + (bRow + rl) * 1024 + bCol + half * 32;
      else          dst = outK + (bRow + rl) * 1024 + (bCol - 1024) + half * 32;
#pragma unroll
      for (int k = 0; k < 4; k++)
        *(ushort8v*)(dst + k * 8) = *(const ushort8v*)(srcp + k * 8);
    }
  }
}

// Flash attention. Grid (bh=64, qt=8). Block = 128 q-rows; 4 waves x 32 rows.
// KV tiles of 64 double-buffered via global_load_lds; ONE barrier per tile.
// SWAPPED QK^T (S^T: q=l15 lane-local); packed u32 Pl writes; ballot-gated deferred-max
// rescale (common path: 31 fmax + 1 __any, no shfl reduce). Q prescaled by 0.125*log2e.
__global__ __launch_bounds__(256, 2)
void attn_kernel(const unsigned short* __restrict__ Qb,
                 const unsigned short* __restrict__ Kb,
                 const unsigned short* __restrict__ Vt_g,
                 const int* __restrict__ maskp,
                 unsigned short* __restrict__ Ob) {
  const int S = 1024, D = 1024;
  __shared__ __align__(16) unsigned short Kl[2][64][64];
  __shared__ __align__(16) unsigned short Vl[2][64][64];
  __shared__ __align__(16) unsigned short Pl[128][64];
  const int tid = threadIdx.x;
  const int lane = tid & 63;
  const int w = tid >> 6;
  const int grp = lane >> 4, l15 = lane & 15;
  const int bh = blockIdx.x;                  // b*16 + h
  const int qt = blockIdx.y;                  // 0..7
  const int b = bh >> 4, h = bh & 15;
  const float NEG = -__builtin_inff();

  // block-uniform mask summary (the bench mask is all-ones -> fast path)
  const int4 mv = *(const int4*)(maskp + b * S + tid * 4);
  const int allLive = __syncthreads_and(mv.x && mv.y && mv.z && mv.w);

  // Q fragments: wave's 32 q-rows (two 16-row groups); used as the MFMA B-operand
  bf16x8 aq[2][2];
#pragma unroll
  for (int m = 0; m < 2; m++) {
    const unsigned short* Qp =
        Qb + ((size_t)(b * S + qt * 128 + w * 32 + m * 16 + l15)) * D + h * 64;
    aq[m][0] = *(const bf16x8*)(Qp + grp * 8);
    aq[m][1] = *(const bf16x8*)(Qp + 32 + grp * 8);
  }

  bf16x8 onesb;
#pragma unroll
  for (int j = 0; j < 8; j++) onesb[j] = (__bf16)1.0f;

  f32x4 acc_o[2][4];
#pragma unroll
  for (int m = 0; m < 2; m++)
#pragma unroll
    for (int f = 0; f < 4; f++) { f32x4 z = {0.f,0.f,0.f,0.f}; acc_o[m][f] = z; }
  f32x4 acc_l[2] = {{0.f,0.f,0.f,0.f}, {0.f,0.f,0.f,0.f}};
  float M = NEG;  // wave-uniform running max (covers all 32 rows)

  // staging geometry: row = rd*32 + tid>>3, source chunk = (tid&7)^(row&7)
  const int srow = tid >> 3;
  const int xc = (((tid & 7) ^ (srow & 7)) << 3);
  const unsigned short* Kg0 = Kb + ((size_t)(b * S + srow)) * D + h * 64 + xc;
  const unsigned short* Kg1 = Kg0 + 32 * (size_t)D;
  const unsigned short* Vgb = Vt_g + (((size_t)bh) << 16);
  const unsigned short* Vg0 = Vgb + (size_t)srow * S + xc;
  const unsigned short* Vg1 = Vg0 + 32 * (size_t)S;

  auto stage = [&](int kt2, int buf) {
    const size_t kb = (size_t)kt2 * 64;
    gload_lds16(Kg0 + kb * D, &Kl[buf][0][0] + w * 512);
    gload_lds16(Kg1 + kb * D, &Kl[buf][0][0] + w * 512 + 2048);
    gload_lds16(Vg0 + kb,     &Vl[buf][0][0] + w * 512);
    gload_lds16(Vg1 + kb,     &Vl[buf][0][0] + w * 512 + 2048);
  };
  stage(0, 0);  // prologue

  for (int kt = 0; kt < 16; ++kt) {
    const int cur = kt & 1;
    const int kbase = kt * 64;
    __syncthreads();  // staged 'cur' resident; tile kt-1 body (buf cur^1 reads) complete
    if (kt < 15) stage(kt + 1, cur ^ 1);  // in flight across whole tile body

    // S^T = K Q^T (swapped operands): st[m][f][r] = S[q=w*32+m*16+l15][kc=f*16+grp*4+r]
    f32x4 sfr[2][4];
    __builtin_amdgcn_s_setprio(1);
#pragma unroll
    for (int f = 0; f < 4; f++) {
      const int R = f * 16 + l15;
      const int p0 = (grp ^ (R & 7)) << 3;
      const int p1 = ((4 + grp) ^ (R & 7)) << 3;
      bf16x8 ak0 = *(const bf16x8*)&Kl[cur][R][p0];   // K[kc][d 0..31]
      bf16x8 ak1 = *(const bf16x8*)&Kl[cur][R][p1];   // d 32..63
#pragma unroll
      for (int m = 0; m < 2; m++) {
        f32x4 z = {0.f,0.f,0.f,0.f};
        z = __builtin_amdgcn_mfma_f32_16x16x32_bf16(ak0, aq[m][0], z, 0, 0, 0);
        z = __builtin_amdgcn_mfma_f32_16x16x32_bf16(ak1, aq[m][1], z, 0, 0, 0);
        sfr[m][f] = z;
      }
    }
    __builtin_amdgcn_s_setprio(0);

    if (!allLive) {  // rare general path: mask as additive bias (kc reg-indexed)
#pragma unroll
      for (int f = 0; f < 4; f++)
#pragma unroll
        for (int r = 0; r < 4; r++) {
          const float biasf = maskp[b * S + kbase + f * 16 + grp * 4 + r] ? 0.f : NEG;
#pragma unroll
          for (int m = 0; m < 2; m++) sfr[m][f][r] += biasf;
        }
    }

    // lane-local max (max3-friendly triples), then ballot-gated wave reduce+rescale.
    float lm = fmaxf(sfr[0][0][0], sfr[0][0][1]);
#pragma unroll
    for (int m = 0; m < 2; m++)
#pragma unroll
      for (int f = 0; f < 4; f++) {
        lm = fmaxf(lm, fmaxf(fmaxf(sfr[m][f][0], sfr[m][f][1]),
                             fmaxf(sfr[m][f][2], sfr[m][f][3])));
      }
    if (__any(lm > M + 8.f)) {   // wave-uniform; fires on tile 0 (M=-inf), then rarely
      float rm = lm;
      rm = fmaxf(rm, __shfl_xor(rm, 1));
      rm = fmaxf(rm, __shfl_xor(rm, 2));
      rm = fmaxf(rm, __shfl_xor(rm, 4));
      rm = fmaxf(rm, __shfl_xor(rm, 8));
      rm = fmaxf(rm, __shfl_xor(rm, 16));
      rm = fmaxf(rm, __shfl_xor(rm, 32));
      const float sc = exp2f(M - rm);  // first tile: 0
      M = rm;
#pragma unroll
      for (int m = 0; m < 2; m++) {
#pragma unroll
        for (int f = 0; f < 4; f++) acc_o[m][f] *= sc;
        acc_l[m] *= sc;
      }
    }

    // P = exp2(st - M): pack r-pairs -> u32, swizzled b32 store into wave-private Pl rows.
#pragma unroll
    for (int m = 0; m < 2; m++) {
      const int Q = w * 32 + m * 16 + l15;
      unsigned short* rowp = &Pl[0][0] + Q * 64;
#pragma unroll
      for (int f = 0; f < 4; f++) {
        const int c = (f * 2 + (grp >> 1)) ^ (l15 & 7);
        const int base = (c << 3) + (grp & 1) * 4;
#pragma unroll
        for (int hh = 0; hh < 2; hh++) {
          const float p0 = exp2f(sfr[m][f][2 * hh] - M);
          const float p1 = exp2f(sfr[m][f][2 * hh + 1] - M);
          const unsigned int pk =
              (unsigned int)f2bf(p0) | ((unsigned int)f2bf(p1) << 16);
          *(unsigned int*)(rowp + base + 2 * hh) = pk;
        }
      }
    }

    // V fragments once, reused by both groups
    bf16x8 bv0[4], bv1[4];
#pragma unroll
    for (int f = 0; f < 4; f++) {
      const int Rv = f * 16 + l15;
      bv0[f] = *(const bf16x8*)&Vl[cur][Rv][((grp ^ (Rv & 7)) << 3)];
      bv1[f] = *(const bf16x8*)&Vl[cur][Rv][(((4 + grp) ^ (Rv & 7)) << 3)];
    }

    // O += P V ; l += P . 1  (Pl RAW handled by intra-wave lgkmcnt)
    __builtin_amdgcn_s_setprio(1);
#pragma unroll
    for (int m = 0; m < 2; m++) {
      const int Q = w * 32 + m * 16 + l15;
      const unsigned short* rowp = &Pl[0][0] + Q * 64;
      const bf16x8 ap0 = *(const bf16x8*)(rowp + ((grp ^ (l15 & 7)) << 3));        // kc 0-31
      const bf16x8 ap1 = *(const bf16x8*)(rowp + (((4 + grp) ^ (l15 & 7)) << 3));  // kc 32-63
#pragma unroll
      for (int f = 0; f < 4; f++) {
        acc_o[m][f] = __builtin_amdgcn_mfma_f32_16x16x32_bf16(ap0, bv0[f], acc_o[m][f], 0, 0, 0);
        acc_o[m][f] = __builtin_amdgcn_mfma_f32_16x16x32_bf16(ap1, bv1[f], acc_o[m][f], 0, 0, 0);
      }
      acc_l[m] = __builtin_amdgcn_mfma_f32_16x16x32_bf16(ap0, onesb, acc_l[m], 0, 0, 0);
      acc_l[m] = __builtin_amdgcn_mfma_f32_16x16x32_bf16(ap1, onesb, acc_l[m], 0, 0, 0);
    }
    __builtin_amdgcn_s_setprio(0);
  }

#pragma unroll
  for (int m = 0; m < 2; m++)
#pragma unroll
    for (int r = 0; r < 4; r++) {
      const float inv = 1.f / acc_l[m][r];
      const int row = qt * 128 + w * 32 + m * 16 + grp * 4 + r;
#pragma unroll
      for (int f = 0; f < 4; f++) {
        const float v = acc_o[m][f][r] * inv;
        Ob[((size_t)(b * S + row)) * D + h * 64 + f * 16 + l15] = f2bf(v);
      }
    }
}

// out = alpha*( (a+b - mean) / (std_ddof1 + eps) ) + beta
// AMODE/BMODE: 0 -> f32, 1 -> bf16. Outputs: optional f32, optional bf16.
template<int AMODE, int BMODE, bool F32OUT, bool BF16OUT>
__global__ __launch_bounds__(256)
void norm_residual(const void* __restrict__ a, const void* __restrict__ bsrc,
                   const float* __restrict__ alpha, const float* __restrict__ beta,
                   float* __restrict__ out, unsigned short* __restrict__ out_bf) {
  const int D = 1024;
  const size_t base = (size_t)blockIdx.x * D + threadIdx.x * 4;
  float a0, a1, a2, a3, b0v, b1v, b2v, b3v;
  if (AMODE == 0) {
    const float4 va = *(const float4*)((const float*)a + base);
    a0 = va.x; a1 = va.y; a2 = va.z; a3 = va.w;
  } else {
    const ushort4v va = *(const ushort4v*)((const unsigned short*)a + base);
    a0 = bf2f(va[0]); a1 = bf2f(va[1]); a2 = bf2f(va[2]); a3 = bf2f(va[3]);
  }
  if (BMODE == 0) {
    const float4 vb = *(const float4*)((const float*)bsrc + base);
    b0v = vb.x; b1v = vb.y; b2v = vb.z; b3v = vb.w;
  } else {
    const ushort4v vb = *(const ushort4v*)((const unsigned short*)bsrc + base);
    b0v = bf2f(vb[0]); b1v = bf2f(vb[1]); b2v = bf2f(vb[2]); b3v = bf2f(vb[3]);
  }
  const float x0 = a0 + b0v, x1 = a1 + b1v, x2 = a2 + b2v, x3 = a3 + b3v;
  float s1 = x0 + x1 + x2 + x3;
  float s2 = x0 * x0 + x1 * x1 + x2 * x2 + x3 * x3;
#pragma unroll
  for (int m = 1; m < 64; m <<= 1) {
    s1 += __shfl_xor(s1, m);
    s2 += __shfl_xor(s2, m);
  }
  __shared__ float red[8];
  const int w = threadIdx.x >> 6, lane = threadIdx.x & 63;
  if (lane == 0) { red[w] = s1; red[4 + w] = s2; }
  __syncthreads();
  s1 = red[0] + red[1] + red[2] + red[3];
  s2 = red[4] + red[5] + red[6] + red[7];
  const float mean = s1 * (1.f / 1024.f);
  const float var = fmaxf((s2 - 1024.f * mean * mean) * (1.f / 1023.f), 0.f);
  const float k = alpha[0] / (sqrtf(var) + 1e-6f);
  const float b0 = beta[0];
  const float y0 = (x0 - mean) * k + b0;
  const float y1 = (x1 - mean) * k + b0;
  const float y2 = (x2 - mean) * k + b0;
  const float y3 = (x3 - mean) * k + b0;
  if (F32OUT) {
    float4 o = {y0, y1, y2, y3};
    *(float4*)(out + base) = o;
  }
  if (BF16OUT) {
    ushort4v ob;
    ob[0] = f2bf(y0); ob[1] = f2bf(y1); ob[2] = f2bf(y2); ob[3] = f2bf(y3);
    *(ushort4v*)(out_bf + base) = ob;
  }
}

extern "C" void kernel_launch(void* const* d_in, const int* in_sizes, int n_in,
                              void* d_out, int out_size, void* d_ws, size_t ws_size,
                              hipStream_t stream) {
  const float* x      = (const float*)d_in[0];
  const int*   maskp  = (const int*)d_in[1];
  const float* Wq_w   = (const float*)d_in[2];
  const float* Wq_b   = (const float*)d_in[3];
  const float* Wk_w   = (const float*)d_in[4];
  const float* Wk_b   = (const float*)d_in[5];
  const float* Wv_w   = (const float*)d_in[6];
  const float* Wv_b   = (const float*)d_in[7];
  const float* Wo_w   = (const float*)d_in[8];
  const float* Wo_b   = (const float*)d_in[9];
  const float* W1_w   = (const float*)d_in[10];
  const float* W1_b   = (const float*)d_in[11];
  const float* W2_w   = (const float*)d_in[12];
  const float* W2_b   = (const float*)d_in[13];
  const float* alpha1 = (const float*)d_in[14];
  const float* beta1  = (const float*)d_in[15];
  const float* alpha2 = (const float*)d_in[16];
  const float* beta2  = (const float*)d_in[17];

  const int B = 4, S = 1024, D = 1024;
  const int M = B * S;  // 4096
  const size_t MiB = 1u << 20;
  char* ws = (char*)d_ws;
  unsigned short* x_bf    = (unsigned short*)(ws + 0 * MiB);   // 8 MiB
  unsigned short* Wqkv_bf = (unsigned short*)(ws + 8 * MiB);   // 6 MiB (Wq|Wk|Wv rows)
  unsigned short* Wo_bf   = (unsigned short*)(ws + 14 * MiB);  // 2 MiB
  unsigned short* W1_bf   = (unsigned short*)(ws + 16 * MiB);
  unsigned short* W2_bf   = (unsigned short*)(ws + 18 * MiB);
  unsigned short* Q_bf    = (unsigned short*)(ws + 20 * MiB);  // 8 MiB (prescaled)
  unsigned short* K_bf    = (unsigned short*)(ws + 28 * MiB);  // 8 MiB
  unsigned short* Vt_bf   = (unsigned short*)(ws + 36 * MiB);  // 8 MiB (pre-transposed V)
  unsigned short* O_bf    = (unsigned short*)(ws + 44 * MiB);  // 8 MiB
  unsigned short* attn_bf = (unsigned short*)(ws + 52 * MiB);  // 8 MiB
  unsigned short* x1_bf   = (unsigned short*)(ws + 20 * MiB);  // reuse Q (dead)
  unsigned short* ff1_bf  = (unsigned short*)(ws + 28 * MiB);  // reuse K (dead)
  unsigned short* ff2_bf  = (unsigned short*)(ws + 36 * MiB);  // reuse Vt (dead)

  cvt_all<<<dim3(1024, 10), dim3(256), 0, stream>>>(
      x, Wq_w, Wk_w, Wv_w, Wo_w, W1_w, W2_w, x_bf, Wqkv_bf, Wo_bf, W1_bf, W2_bf);

  // fused QKV: C[4096,3072]; BM=128/BN=64; seg0->Q rm (prescaled), seg1->K rm, seg2->V^T
  gemm_bt<128, false, 2><<<dim3(32 * 48), dim3(256), 0, stream>>>(
      x_bf, Wqkv_bf, Wq_b, Wk_b, Wv_b, Q_bf, K_bf, Vt_bf, M, 3072, D);

  attn_kernel<<<dim3(B * 16, S / 128), dim3(256), 0, stream>>>(Q_bf, K_bf, Vt_bf, maskp, O_bf);

  gemm_bt<64, false, 1><<<dim3(64 * 16), dim3(256), 0, stream>>>(
      O_bf, Wo_bf, Wo_b, nullptr, nullptr, attn_bf, nullptr, nullptr, M, D, D);
  norm_residual<0, 1, false, true><<<dim3(M), dim3(256), 0, stream>>>(
      x, attn_bf, alpha1, beta1, nullptr, x1_bf);
  gemm_bt<64, true, 1><<<dim3(64 * 16), dim3(256), 0, stream>>>(
      x1_bf, W1_bf, W1_b, nullptr, nullptr, ff1_bf, nullptr, nullptr, M, D, D);
  gemm_bt<64, false, 1><<<dim3(64 * 16), dim3(256), 0, stream>>>(
      ff1_bf, W2_bf, W2_b, nullptr, nullptr, ff2_bf, nullptr, nullptr, M, D, D);
  norm_residual<1, 1, true, false><<<dim3(M), dim3(256), 0, stream>>>(
      x1_bf, ff2_bf, alpha2, beta2, (float*)d_out, nullptr);
}

// Round 20
// 152.467 us; speedup vs baseline: 1.0354x; 1.0354x over previous
//
#include <hip/hip_runtime.h>

// Encoder block: x:(4,1024,1024) f32. Fused-QKV proj -> MHA(16 heads) -> Wo -> +res -> norm
// (ddof=1) -> FF(relu) -> +res -> norm. bf16 MFMA GEMMs, fp32 norms.
// R20 (FINAL): revert to R18, the best-measured configuration (152.6us). R19's BM=128 QKV
// regressed (occupancy 36->26%, total +5us). The 2-phase GEMM structure is measured-null
// across all knobs (BN/BM/BK/occupancy/vmcnt/XCD-remap); this is the converged kernel.

typedef __bf16 bf16x8 __attribute__((ext_vector_type(8)));
typedef float f32x4 __attribute__((ext_vector_type(4)));
typedef unsigned short ushort4v __attribute__((ext_vector_type(4)));
typedef unsigned short ushort8v __attribute__((ext_vector_type(8)));

static __device__ __forceinline__ unsigned short f2bf(float f) {
  return __builtin_bit_cast(unsigned short, (__bf16)f);  // HW RNE cvt
}
static __device__ __forceinline__ float bf2f(unsigned short u) {
  return __builtin_bit_cast(float, (unsigned int)u << 16);
}

static __device__ __forceinline__ void gload_lds16(const void* g, void* l) {
  __builtin_amdgcn_global_load_lds(
      (const __attribute__((address_space(1))) unsigned int*)g,
      (__attribute__((address_space(3))) unsigned int*)l, 16, 0, 0);
}

// One launch: y=0..3 -> x quarters; y=4..6 -> Wq/Wk/Wv into concat; y=7..9 -> Wo/W1/W2.
__global__ __launch_bounds__(256)
void cvt_all(const float* __restrict__ x, const float* __restrict__ wq,
             const float* __restrict__ wk, const float* __restrict__ wv,
             const float* __restrict__ wo, const float* __restrict__ w1,
             const float* __restrict__ w2,
             unsigned short* __restrict__ x_bf, unsigned short* __restrict__ wqkv_bf,
             unsigned short* __restrict__ wo_bf, unsigned short* __restrict__ w1_bf,
             unsigned short* __restrict__ w2_bf) {
  const int y = blockIdx.y;
  const size_t MEL = 1u << 20;
  const float* src;
  unsigned short* dst;
  switch (y) {
    case 0: case 1: case 2: case 3: src = x + y * MEL; dst = x_bf + y * MEL; break;
    case 4: src = wq; dst = wqkv_bf; break;
    case 5: src = wk; dst = wqkv_bf + MEL; break;
    case 6: src = wv; dst = wqkv_bf + 2 * MEL; break;
    case 7: src = wo; dst = wo_bf; break;
    case 8: src = w1; dst = w1_bf; break;
    default: src = w2; dst = w2_bf; break;
  }
  const int i = blockIdx.x * 256 + threadIdx.x;
  const float4 v = reinterpret_cast<const float4*>(src)[i];
  ushort4v o;
  o[0] = f2bf(v.x); o[1] = f2bf(v.y); o[2] = f2bf(v.z); o[3] = f2bf(v.w);
  reinterpret_cast<ushort4v*>(dst)[i] = o;
}

// C[M,N] = A[M,K] @ W[N,K]^T + bias. BM=64, BN=BNT, BK=64, 4 waves (2x2),
// wave tile 32 x BNT/2. 2-phase dbuf LDS, one barrier per K-step, prefetch under MFMAs,
// XOR-swizzled LDS (16B chunk c of row r holds k-chunk c^(r&7)).
// 1D grid, XCD-partitioned remap (M==4096, nwg%8==0): XCD c owns row-panels c*8..c*8+7
// (A slice 1MB -> L2-resident) and sweeps columns.
// OUT_MODE: 1 = bf16 rm scalar stores (opt RELU); 2 = fused QKV split via LDS-coalesced
//   epilogue (seg=bCol>>10: 0 Q rm prescaled by 0.125*log2e, 1 K rm,
//   2 V^T [(b*16+h)][d][s] with swizzled C-tile). OUT_MODE 2 uses BNT=64.
template<int BNT, bool RELU, int OUT_MODE>
__global__ __launch_bounds__(256, (BNT == 64 ? 4 : 2))
void gemm_bt(const unsigned short* __restrict__ A,
             const unsigned short* __restrict__ W,
             const float* __restrict__ bias0, const float* __restrict__ bias1,
             const float* __restrict__ bias2,
             void* __restrict__ out0, unsigned short* __restrict__ outK,
             unsigned short* __restrict__ outVt, int M, int N, int K) {
  constexpr int NFR = BNT / 32;                 // N-frags per wave
  __shared__ __align__(16) unsigned short Al[2][64][64];
  __shared__ __align__(16) unsigned short Bl[2][BNT][64];
  const int tid = threadIdx.x;
  const int lane = tid & 63;
  const int w = tid >> 6;
  const int wr = w >> 1, wc = w & 1;
  const int grp = lane >> 4, l15 = lane & 15;
  // XCD-partitioned decomposition of the 1D block id
  const int bid = blockIdx.x;
  const int xcd = bid & 7;
  const int li = bid >> 3;
  const long bRow = (long)(xcd * 8 + (li & 7)) * 64;
  const long bCol = (long)(li >> 3) * BNT;

  f32x4 acc[2][NFR];
#pragma unroll
  for (int m = 0; m < 2; m++)
#pragma unroll
    for (int n = 0; n < NFR; n++) { f32x4 z = {0.f,0.f,0.f,0.f}; acc[m][n] = z; }

  const int srow = tid >> 3;                    // 0..31
  const int xc = (((tid & 7) ^ (srow & 7)) << 3);
  const unsigned short* Ag0 = A + (bRow + srow) * (long)K + xc;
  const unsigned short* Ag1 = Ag0 + 32L * K;
  const unsigned short* Wg0 = W + (bCol + srow) * (long)K + xc;
  const unsigned short* Wg1 = Wg0 + 32L * K;
  const unsigned short* Wg2 = (BNT == 128) ? Wg0 + 64L * K : nullptr;
  const unsigned short* Wg3 = (BNT == 128) ? Wg0 + 96L * K : nullptr;

  auto stage = [&](int k0, int buf) {
    unsigned short* ldsA = &Al[buf][0][0] + w * 512;   // wave-uniform base
    unsigned short* ldsB = &Bl[buf][0][0] + w * 512;
    gload_lds16(Ag0 + k0, ldsA);
    gload_lds16(Ag1 + k0, ldsA + 2048);
    gload_lds16(Wg0 + k0, ldsB);
    gload_lds16(Wg1 + k0, ldsB + 2048);
    if constexpr (BNT == 128) {
      gload_lds16(Wg2 + k0, ldsB + 4096);
      gload_lds16(Wg3 + k0, ldsB + 6144);
    }
  };

  const int NT = K >> 6;
  stage(0, 0);
  for (int t = 0; t < NT; ++t) {
    const int cur = t & 1;
    __syncthreads();  // drains vmcnt: buf[cur] resident; buf[cur^1] readers (t-1) done
    if (t + 1 < NT) stage((t + 1) << 6, cur ^ 1);  // in flight under MFMAs
#pragma unroll
    for (int kk = 0; kk < 2; kk++) {
      bf16x8 af[2], bfr[NFR];
#pragma unroll
      for (int m = 0; m < 2; m++) {
        const int R = wr * 32 + m * 16 + l15;
        const int pos = (kk * 4 + grp) ^ (R & 7);
        af[m] = *(const bf16x8*)&Al[cur][R][pos << 3];
      }
#pragma unroll
      for (int n = 0; n < NFR; n++) {
        const int R = wc * (BNT / 2) + n * 16 + l15;
        const int pos = (kk * 4 + grp) ^ (R & 7);
        bfr[n] = *(const bf16x8*)&Bl[cur][R][pos << 3];
      }
#pragma unroll
      for (int m = 0; m < 2; m++)
#pragma unroll
        for (int n = 0; n < NFR; n++)
          acc[m][n] = __builtin_amdgcn_mfma_f32_16x16x32_bf16(af[m], bfr[n], acc[m][n], 0, 0, 0);
    }
  }

  const float QSCL = 0.125f * 1.44269504088896340736f;  // folded softmax scale (seg 0)

  if (OUT_MODE == 1) {
    // direct scalar stores
#pragma unroll
    for (int n = 0; n < NFR; n++) {
      const long col = bCol + wc * (BNT / 2) + n * 16 + l15;
      const float bv = bias0[col];
#pragma unroll
      for (int m = 0; m < 2; m++) {
        const long row0 = bRow + wr * 32 + m * 16 + grp * 4;
#pragma unroll
        for (int r = 0; r < 4; r++) {
          float v = acc[m][n][r] + bv;
          if (RELU) v = fmaxf(v, 0.f);
          ((unsigned short*)out0)[(row0 + r) * (long)N + col] = f2bf(v);
        }
      }
    }
  } else {
    // QKV: epilogue through LDS (Al reused) -> coalesced 16B stores
    const int seg = (int)(bCol >> 10);
    const float* bp = (seg == 0 ? bias0 : seg == 1 ? bias1 : bias2);
    unsigned short* Cl = &Al[0][0][0];
    __syncthreads();  // all frag reads done; Al reusable
#pragma unroll
    for (int n = 0; n < NFR; n++) {
      const int cc = wc * (BNT / 2) + n * 16 + l15;     // 0..BNT-1 block-col
      const long col = bCol + cc;
      const float bv = bp[col & 1023];
#pragma unroll
      for (int m = 0; m < 2; m++) {
        const int row0 = wr * 32 + m * 16 + grp * 4;    // block-row
#pragma unroll
        for (int r = 0; r < 4; r++) {
          const int rl = row0 + r;
          float v = acc[m][n][r] + bv;
          if (seg == 0) v *= QSCL;
          if (seg == 2) Cl[cc * 64 + (rl ^ ((cc & 7) << 3))] = f2bf(v);  // swizzled [BNT][64]
          else          Cl[rl * BNT + cc] = f2bf(v);                     // [64][BNT]
        }
      }
    }
    __syncthreads();
    if (seg == 2) {
      // block spans exactly one head slab (BNT=64): head=(bCol&1023)>>6, d=cc
      const int cc = tid >> 2;              // 0..63
      const int part = tid & 3;             // s-quarter of the 64-row tile
      const long bidx = (bRow >> 10) * 16 + (((long)(bCol & 1023)) >> 6);
      unsigned short* dst = outVt + (bidx << 16) + ((long)cc << 10) +
                            (bRow & 1023) + part * 16;
#pragma unroll
      for (int k = 0; k < 2; k++) {
        const int g = part * 2 + k;         // s-group: rows g*8..g*8+7
        *(ushort8v*)(dst + k * 8) =
            *(const ushort8v*)(Cl + cc * 64 + ((g ^ (cc & 7)) << 3));
      }
    } else {
      const int rl = tid >> 2;              // 0..63
      const int q = tid & 3;                // 16-col quarter
      const unsigned short* srcp = Cl + rl * 64 + q * 16;
      unsigned short* dst;
      if (seg == 0) dst = (unsigned short*)out0 + (bRow + rl) * 1024 + bCol + q * 16;
      else          dst = outK + (bRow + rl) * 1024 + (bCol - 1024) + q * 16;
#pragma unroll
      for (int k = 0; k < 2; k++)
        *(ushort8v*)(dst + k * 8) = *(const ushort8v*)(srcp + k * 8);
    }
  }
}

// Flash attention. Grid (bh=64, qt=8). Block = 128 q-rows; 4 waves x 32 rows.
// KV tiles of 64 double-buffered via global_load_lds; ONE barrier per tile.
// SWAPPED QK^T (S^T: q=l15 lane-local); packed u32 Pl writes; ballot-gated deferred-max
// rescale (common path: 31 fmax + 1 __any, no shfl reduce). Q prescaled by 0.125*log2e.
__global__ __launch_bounds__(256, 2)
void attn_kernel(const unsigned short* __restrict__ Qb,
                 const unsigned short* __restrict__ Kb,
                 const unsigned short* __restrict__ Vt_g,
                 const int* __restrict__ maskp,
                 unsigned short* __restrict__ Ob) {
  const int S = 1024, D = 1024;
  __shared__ __align__(16) unsigned short Kl[2][64][64];
  __shared__ __align__(16) unsigned short Vl[2][64][64];
  __shared__ __align__(16) unsigned short Pl[128][64];
  const int tid = threadIdx.x;
  const int lane = tid & 63;
  const int w = tid >> 6;
  const int grp = lane >> 4, l15 = lane & 15;
  const int bh = blockIdx.x;                  // b*16 + h
  const int qt = blockIdx.y;                  // 0..7
  const int b = bh >> 4, h = bh & 15;
  const float NEG = -__builtin_inff();

  // block-uniform mask summary (the bench mask is all-ones -> fast path)
  const int4 mv = *(const int4*)(maskp + b * S + tid * 4);
  const int allLive = __syncthreads_and(mv.x && mv.y && mv.z && mv.w);

  // Q fragments: wave's 32 q-rows (two 16-row groups); used as the MFMA B-operand
  bf16x8 aq[2][2];
#pragma unroll
  for (int m = 0; m < 2; m++) {
    const unsigned short* Qp =
        Qb + ((size_t)(b * S + qt * 128 + w * 32 + m * 16 + l15)) * D + h * 64;
    aq[m][0] = *(const bf16x8*)(Qp + grp * 8);
    aq[m][1] = *(const bf16x8*)(Qp + 32 + grp * 8);
  }

  bf16x8 onesb;
#pragma unroll
  for (int j = 0; j < 8; j++) onesb[j] = (__bf16)1.0f;

  f32x4 acc_o[2][4];
#pragma unroll
  for (int m = 0; m < 2; m++)
#pragma unroll
    for (int f = 0; f < 4; f++) { f32x4 z = {0.f,0.f,0.f,0.f}; acc_o[m][f] = z; }
  f32x4 acc_l[2] = {{0.f,0.f,0.f,0.f}, {0.f,0.f,0.f,0.f}};
  float M = NEG;  // wave-uniform running max (covers all 32 rows)

  // staging geometry: row = rd*32 + tid>>3, source chunk = (tid&7)^(row&7)
  const int srow = tid >> 3;
  const int xc = (((tid & 7) ^ (srow & 7)) << 3);
  const unsigned short* Kg0 = Kb + ((size_t)(b * S + srow)) * D + h * 64 + xc;
  const unsigned short* Kg1 = Kg0 + 32 * (size_t)D;
  const unsigned short* Vgb = Vt_g + (((size_t)bh) << 16);
  const unsigned short* Vg0 = Vgb + (size_t)srow * S + xc;
  const unsigned short* Vg1 = Vg0 + 32 * (size_t)S;

  auto stage = [&](int kt2, int buf) {
    const size_t kb = (size_t)kt2 * 64;
    gload_lds16(Kg0 + kb * D, &Kl[buf][0][0] + w * 512);
    gload_lds16(Kg1 + kb * D, &Kl[buf][0][0] + w * 512 + 2048);
    gload_lds16(Vg0 + kb,     &Vl[buf][0][0] + w * 512);
    gload_lds16(Vg1 + kb,     &Vl[buf][0][0] + w * 512 + 2048);
  };
  stage(0, 0);  // prologue

  for (int kt = 0; kt < 16; ++kt) {
    const int cur = kt & 1;
    const int kbase = kt * 64;
    __syncthreads();  // staged 'cur' resident; tile kt-1 body (buf cur^1 reads) complete
    if (kt < 15) stage(kt + 1, cur ^ 1);  // in flight across whole tile body

    // S^T = K Q^T (swapped operands): st[m][f][r] = S[q=w*32+m*16+l15][kc=f*16+grp*4+r]
    f32x4 sfr[2][4];
    __builtin_amdgcn_s_setprio(1);
#pragma unroll
    for (int f = 0; f < 4; f++) {
      const int R = f * 16 + l15;
      const int p0 = (grp ^ (R & 7)) << 3;
      const int p1 = ((4 + grp) ^ (R & 7)) << 3;
      bf16x8 ak0 = *(const bf16x8*)&Kl[cur][R][p0];   // K[kc][d 0..31]
      bf16x8 ak1 = *(const bf16x8*)&Kl[cur][R][p1];   // d 32..63
#pragma unroll
      for (int m = 0; m < 2; m++) {
        f32x4 z = {0.f,0.f,0.f,0.f};
        z = __builtin_amdgcn_mfma_f32_16x16x32_bf16(ak0, aq[m][0], z, 0, 0, 0);
        z = __builtin_amdgcn_mfma_f32_16x16x32_bf16(ak1, aq[m][1], z, 0, 0, 0);
        sfr[m][f] = z;
      }
    }
    __builtin_amdgcn_s_setprio(0);

    if (!allLive) {  // rare general path: mask as additive bias (kc reg-indexed)
#pragma unroll
      for (int f = 0; f < 4; f++)
#pragma unroll
        for (int r = 0; r < 4; r++) {
          const float biasf = maskp[b * S + kbase + f * 16 + grp * 4 + r] ? 0.f : NEG;
#pragma unroll
          for (int m = 0; m < 2; m++) sfr[m][f][r] += biasf;
        }
    }

    // lane-local max (max3-friendly triples), then ballot-gated wave reduce+rescale.
    float lm = fmaxf(sfr[0][0][0], sfr[0][0][1]);
#pragma unroll
    for (int m = 0; m < 2; m++)
#pragma unroll
      for (int f = 0; f < 4; f++) {
        lm = fmaxf(lm, fmaxf(fmaxf(sfr[m][f][0], sfr[m][f][1]),
                             fmaxf(sfr[m][f][2], sfr[m][f][3])));
      }
    if (__any(lm > M + 8.f)) {   // wave-uniform; fires on tile 0 (M=-inf), then rarely
      float rm = lm;
      rm = fmaxf(rm, __shfl_xor(rm, 1));
      rm = fmaxf(rm, __shfl_xor(rm, 2));
      rm = fmaxf(rm, __shfl_xor(rm, 4));
      rm = fmaxf(rm, __shfl_xor(rm, 8));
      rm = fmaxf(rm, __shfl_xor(rm, 16));
      rm = fmaxf(rm, __shfl_xor(rm, 32));
      const float sc = exp2f(M - rm);  // first tile: 0
      M = rm;
#pragma unroll
      for (int m = 0; m < 2; m++) {
#pragma unroll
        for (int f = 0; f < 4; f++) acc_o[m][f] *= sc;
        acc_l[m] *= sc;
      }
    }

    // P = exp2(st - M): pack r-pairs -> u32, swizzled b32 store into wave-private Pl rows.
#pragma unroll
    for (int m = 0; m < 2; m++) {
      const int Q = w * 32 + m * 16 + l15;
      unsigned short* rowp = &Pl[0][0] + Q * 64;
#pragma unroll
      for (int f = 0; f < 4; f++) {
        const int c = (f * 2 + (grp >> 1)) ^ (l15 & 7);
        const int base = (c << 3) + (grp & 1) * 4;
#pragma unroll
        for (int hh = 0; hh < 2; hh++) {
          const float p0 = exp2f(sfr[m][f][2 * hh] - M);
          const float p1 = exp2f(sfr[m][f][2 * hh + 1] - M);
          const unsigned int pk =
              (unsigned int)f2bf(p0) | ((unsigned int)f2bf(p1) << 16);
          *(unsigned int*)(rowp + base + 2 * hh) = pk;
        }
      }
    }

    // V fragments once, reused by both groups
    bf16x8 bv0[4], bv1[4];
#pragma unroll
    for (int f = 0; f < 4; f++) {
      const int Rv = f * 16 + l15;
      bv0[f] = *(const bf16x8*)&Vl[cur][Rv][((grp ^ (Rv & 7)) << 3)];
      bv1[f] = *(const bf16x8*)&Vl[cur][Rv][(((4 + grp) ^ (Rv & 7)) << 3)];
    }

    // O += P V ; l += P . 1  (Pl RAW handled by intra-wave lgkmcnt)
    __builtin_amdgcn_s_setprio(1);
#pragma unroll
    for (int m = 0; m < 2; m++) {
      const int Q = w * 32 + m * 16 + l15;
      const unsigned short* rowp = &Pl[0][0] + Q * 64;
      const bf16x8 ap0 = *(const bf16x8*)(rowp + ((grp ^ (l15 & 7)) << 3));        // kc 0-31
      const bf16x8 ap1 = *(const bf16x8*)(rowp + (((4 + grp) ^ (l15 & 7)) << 3));  // kc 32-63
#pragma unroll
      for (int f = 0; f < 4; f++) {
        acc_o[m][f] = __builtin_amdgcn_mfma_f32_16x16x32_bf16(ap0, bv0[f], acc_o[m][f], 0, 0, 0);
        acc_o[m][f] = __builtin_amdgcn_mfma_f32_16x16x32_bf16(ap1, bv1[f], acc_o[m][f], 0, 0, 0);
      }
      acc_l[m] = __builtin_amdgcn_mfma_f32_16x16x32_bf16(ap0, onesb, acc_l[m], 0, 0, 0);
      acc_l[m] = __builtin_amdgcn_mfma_f32_16x16x32_bf16(ap1, onesb, acc_l[m], 0, 0, 0);
    }
    __builtin_amdgcn_s_setprio(0);
  }

#pragma unroll
  for (int m = 0; m < 2; m++)
#pragma unroll
    for (int r = 0; r < 4; r++) {
      const float inv = 1.f / acc_l[m][r];
      const int row = qt * 128 + w * 32 + m * 16 + grp * 4 + r;
#pragma unroll
      for (int f = 0; f < 4; f++) {
        const float v = acc_o[m][f][r] * inv;
        Ob[((size_t)(b * S + row)) * D + h * 64 + f * 16 + l15] = f2bf(v);
      }
    }
}

// out = alpha*( (a+b - mean) / (std_ddof1 + eps) ) + beta
// AMODE/BMODE: 0 -> f32, 1 -> bf16. Outputs: optional f32, optional bf16.
template<int AMODE, int BMODE, bool F32OUT, bool BF16OUT>
__global__ __launch_bounds__(256)
void norm_residual(const void* __restrict__ a, const void* __restrict__ bsrc,
                   const float* __restrict__ alpha, const float* __restrict__ beta,
                   float* __restrict__ out, unsigned short* __restrict__ out_bf) {
  const int D = 1024;
  const size_t base = (size_t)blockIdx.x * D + threadIdx.x * 4;
  float a0, a1, a2, a3, b0v, b1v, b2v, b3v;
  if (AMODE == 0) {
    const float4 va = *(const float4*)((const float*)a + base);
    a0 = va.x; a1 = va.y; a2 = va.z; a3 = va.w;
  } else {
    const ushort4v va = *(const ushort4v*)((const unsigned short*)a + base);
    a0 = bf2f(va[0]); a1 = bf2f(va[1]); a2 = bf2f(va[2]); a3 = bf2f(va[3]);
  }
  if (BMODE == 0) {
    const float4 vb = *(const float4*)((const float*)bsrc + base);
    b0v = vb.x; b1v = vb.y; b2v = vb.z; b3v = vb.w;
  } else {
    const ushort4v vb = *(const ushort4v*)((const unsigned short*)bsrc + base);
    b0v = bf2f(vb[0]); b1v = bf2f(vb[1]); b2v = bf2f(vb[2]); b3v = bf2f(vb[3]);
  }
  const float x0 = a0 + b0v, x1 = a1 + b1v, x2 = a2 + b2v, x3 = a3 + b3v;
  float s1 = x0 + x1 + x2 + x3;
  float s2 = x0 * x0 + x1 * x1 + x2 * x2 + x3 * x3;
#pragma unroll
  for (int m = 1; m < 64; m <<= 1) {
    s1 += __shfl_xor(s1, m);
    s2 += __shfl_xor(s2, m);
  }
  __shared__ float red[8];
  const int w = threadIdx.x >> 6, lane = threadIdx.x & 63;
  if (lane == 0) { red[w] = s1; red[4 + w] = s2; }
  __syncthreads();
  s1 = red[0] + red[1] + red[2] + red[3];
  s2 = red[4] + red[5] + red[6] + red[7];
  const float mean = s1 * (1.f / 1024.f);
  const float var = fmaxf((s2 - 1024.f * mean * mean) * (1.f / 1023.f), 0.f);
  const float k = alpha[0] / (sqrtf(var) + 1e-6f);
  const float b0 = beta[0];
  const float y0 = (x0 - mean) * k + b0;
  const float y1 = (x1 - mean) * k + b0;
  const float y2 = (x2 - mean) * k + b0;
  const float y3 = (x3 - mean) * k + b0;
  if (F32OUT) {
    float4 o = {y0, y1, y2, y3};
    *(float4*)(out + base) = o;
  }
  if (BF16OUT) {
    ushort4v ob;
    ob[0] = f2bf(y0); ob[1] = f2bf(y1); ob[2] = f2bf(y2); ob[3] = f2bf(y3);
    *(ushort4v*)(out_bf + base) = ob;
  }
}

extern "C" void kernel_launch(void* const* d_in, const int* in_sizes, int n_in,
                              void* d_out, int out_size, void* d_ws, size_t ws_size,
                              hipStream_t stream) {
  const float* x      = (const float*)d_in[0];
  const int*   maskp  = (const int*)d_in[1];
  const float* Wq_w   = (const float*)d_in[2];
  const float* Wq_b   = (const float*)d_in[3];
  const float* Wk_w   = (const float*)d_in[4];
  const float* Wk_b   = (const float*)d_in[5];
  const float* Wv_w   = (const float*)d_in[6];
  const float* Wv_b   = (const float*)d_in[7];
  const float* Wo_w   = (const float*)d_in[8];
  const float* Wo_b   = (const float*)d_in[9];
  const float* W1_w   = (const float*)d_in[10];
  const float* W1_b   = (const float*)d_in[11];
  const float* W2_w   = (const float*)d_in[12];
  const float* W2_b   = (const float*)d_in[13];
  const float* alpha1 = (const float*)d_in[14];
  const float* beta1  = (const float*)d_in[15];
  const float* alpha2 = (const float*)d_in[16];
  const float* beta2  = (const float*)d_in[17];

  const int B = 4, S = 1024, D = 1024;
  const int M = B * S;  // 4096
  const size_t MiB = 1u << 20;
  char* ws = (char*)d_ws;
  unsigned short* x_bf    = (unsigned short*)(ws + 0 * MiB);   // 8 MiB
  unsigned short* Wqkv_bf = (unsigned short*)(ws + 8 * MiB);   // 6 MiB (Wq|Wk|Wv rows)
  unsigned short* Wo_bf   = (unsigned short*)(ws + 14 * MiB);  // 2 MiB
  unsigned short* W1_bf   = (unsigned short*)(ws + 16 * MiB);
  unsigned short* W2_bf   = (unsigned short*)(ws + 18 * MiB);
  unsigned short* Q_bf    = (unsigned short*)(ws + 20 * MiB);  // 8 MiB (prescaled)
  unsigned short* K_bf    = (unsigned short*)(ws + 28 * MiB);  // 8 MiB
  unsigned short* Vt_bf   = (unsigned short*)(ws + 36 * MiB);  // 8 MiB (pre-transposed V)
  unsigned short* O_bf    = (unsigned short*)(ws + 44 * MiB);  // 8 MiB
  unsigned short* attn_bf = (unsigned short*)(ws + 52 * MiB);  // 8 MiB
  unsigned short* x1_bf   = (unsigned short*)(ws + 20 * MiB);  // reuse Q (dead)
  unsigned short* ff1_bf  = (unsigned short*)(ws + 28 * MiB);  // reuse K (dead)
  unsigned short* ff2_bf  = (unsigned short*)(ws + 36 * MiB);  // reuse Vt (dead)

  cvt_all<<<dim3(1024, 10), dim3(256), 0, stream>>>(
      x, Wq_w, Wk_w, Wv_w, Wo_w, W1_w, W2_w, x_bf, Wqkv_bf, Wo_bf, W1_bf, W2_bf);

  // fused QKV: C[4096,3072]; seg0->Q rm (prescaled), seg1->K rm, seg2->V transposed
  gemm_bt<64, false, 2><<<dim3(64 * 48), dim3(256), 0, stream>>>(
      x_bf, Wqkv_bf, Wq_b, Wk_b, Wv_b, Q_bf, K_bf, Vt_bf, M, 3072, D);

  attn_kernel<<<dim3(B * 16, S / 128), dim3(256), 0, stream>>>(Q_bf, K_bf, Vt_bf, maskp, O_bf);

  gemm_bt<64, false, 1><<<dim3(64 * 16), dim3(256), 0, stream>>>(
      O_bf, Wo_bf, Wo_b, nullptr, nullptr, attn_bf, nullptr, nullptr, M, D, D);
  norm_residual<0, 1, false, true><<<dim3(M), dim3(256), 0, stream>>>(
      x, attn_bf, alpha1, beta1, nullptr, x1_bf);
  gemm_bt<64, true, 1><<<dim3(64 * 16), dim3(256), 0, stream>>>(
      x1_bf, W1_bf, W1_b, nullptr, nullptr, ff1_bf, nullptr, nullptr, M, D, D);
  gemm_bt<64, false, 1><<<dim3(64 * 16), dim3(256), 0, stream>>>(
      ff1_bf, W2_bf, W2_b, nullptr, nullptr, ff2_bf, nullptr, nullptr, M, D, D);
  norm_residual<1, 1, true, false><<<dim3(M), dim3(256), 0, stream>>>(
      x1_bf, ff2_bf, alpha2, beta2, (float*)d_out, nullptr);
}